// Round 1
// baseline (517.629 us; speedup 1.0000x reference)
//
#include <hip/hip_runtime.h>

#define EPS_F 0.1f
#define A_F 100.0f
#define NUMNEG_F 10.0f

__global__ __launch_bounds__(256) void grp_edge_kernel(
    const float* __restrict__ x,
    const int* __restrict__ u_idx,
    const int* __restrict__ v_idx,
    float* __restrict__ out,   // out[0]=energy, out+1 = grad (N*64)
    int E)
{
    const int lane = threadIdx.x & 63;
    const int wave_in_block = threadIdx.x >> 6;
    const int waves_per_block = blockDim.x >> 6;
    const int wave = blockIdx.x * waves_per_block + wave_in_block;
    const int nwaves = gridDim.x * waves_per_block;
    const float sign = (lane == 0) ? -1.0f : 1.0f;  // Minkowski J
    float* __restrict__ grad = out + 1;

    float eacc = 0.0f;

    for (int e = wave; e < E; e += nwaves) {
        const int u = u_idx[e];
        const int v = v_idx[e];
        const float xu = x[(size_t)u * 64 + lane];
        const float xv = x[(size_t)v * 64 + lane];
        float p = xu * xv * sign;
        // 64-lane butterfly reduction; result bitwise-identical in all lanes
        #pragma unroll
        for (int off = 32; off >= 1; off >>= 1)
            p += __shfl_xor(p, off, 64);
        const float inner = fminf(p, -1.0f - 1e-7f);
        const float dist = acoshf(-inner);
        if (dist < EPS_F) {
            const float delta = EPS_F - dist;
            eacc += delta * delta;
            const float denom = sqrtf(inner * inner - 1.0f);
            const float factor = -(A_F * delta / NUMNEG_F) / (denom + 1e-9f);
            atomicAdd(&grad[(size_t)u * 64 + lane], factor * xv * sign);
            atomicAdd(&grad[(size_t)v * 64 + lane], factor * xu * sign);
        }
    }

    if (lane == 0 && eacc != 0.0f) {
        atomicAdd(&out[0], 0.5f * A_F * eacc / NUMNEG_F);
    }
}

extern "C" void kernel_launch(void* const* d_in, const int* in_sizes, int n_in,
                              void* d_out, int out_size, void* d_ws, size_t ws_size,
                              hipStream_t stream) {
    const float* x     = (const float*)d_in[0];
    const int*   u_idx = (const int*)d_in[1];
    const int*   v_idx = (const int*)d_in[2];
    float* out = (float*)d_out;
    const int E = in_sizes[1];

    // d_out is poisoned with 0xAA before every timed launch; zero it (async, capture-safe)
    hipMemsetAsync(d_out, 0, (size_t)out_size * sizeof(float), stream);

    // grid-stride over edges, one wave (64 lanes) per edge
    const int blocks = 4096;  // 16384 waves, ~61 edges each
    grp_edge_kernel<<<blocks, 256, 0, stream>>>(x, u_idx, v_idx, out, E);
}